// Round 4
// baseline (6668.970 us; speedup 1.0000x reference)
//
#include <hip/hip_runtime.h>
#include <hip/hip_bf16.h>

// 2-layer LSTM (B=256,T=512,IN=H=256) + FC(128) + log_softmax on MI355X.
//
// Single pipelined kernel: 256 wgs = 2 roles (layer0/layer1, role=bx&1)
// x 16 batch-tiles x 8 j-tiles; 16 independent per-batch-tile pipelines, so
// total time = 513 x per-step exchange latency. LDS-free: MFMA B-fragments
// (lane=batch row, 8 contiguous k) load straight from row-major global.
// W lives in VGPRs all kernel as SPLIT bf16 (hi=trunc, lo=residual): matmuls
// use Whi*uhi + Whi*ulo + Wlo*uhi => ~fp32 accuracy (residual ~2^-17), since
// CDNA4 has no fp32 MFMA. Recurrent h crosses wgs as hi/lo bf16 planes; the
// only plain-bf16 hand-off is layer0->layer1 (error ~5e-4, non-recurrent).
// Sync: per-producer release flags + wave-parallel relaxed polls + acquire
// fence (agent scope: correct under XCD-split L2). u-path (x / h1) runs
// AFTER the release signal so it overlaps the flag round-trip.
//
// Workspace need: ~66 MB (guarded; layout at kernel_launch).

using u16 = unsigned short;
typedef __attribute__((ext_vector_type(8))) short bf16x8;  // 8 bf16 = 4 VGPR
typedef __attribute__((ext_vector_type(4))) float f32x4;

#define T_SEQ 512
#define HDIM  256

__device__ __forceinline__ u16 f2bf(float x) {            // RNE fp32->bf16
  unsigned b = __float_as_uint(x);
  return (u16)((b + 0x7FFFu + ((b >> 16) & 1u)) >> 16);
}
__device__ __forceinline__ float bf2f(u16 h) { return __uint_as_float(((unsigned)h) << 16); }
__device__ __forceinline__ u16 bfhi(float v) { return (u16)(__float_as_uint(v) >> 16); }   // trunc
__device__ __forceinline__ u16 bflo(float v) { return f2bf(v - bf2f(bfhi(v))); }           // residual

__device__ __forceinline__ void split44(float4 a, float4 b, bf16x8& hi, bf16x8& lo) {
  hi[0]=(short)bfhi(a.x); lo[0]=(short)bflo(a.x);
  hi[1]=(short)bfhi(a.y); lo[1]=(short)bflo(a.y);
  hi[2]=(short)bfhi(a.z); lo[2]=(short)bflo(a.z);
  hi[3]=(short)bfhi(a.w); lo[3]=(short)bflo(a.w);
  hi[4]=(short)bfhi(b.x); lo[4]=(short)bflo(b.x);
  hi[5]=(short)bfhi(b.y); lo[5]=(short)bflo(b.y);
  hi[6]=(short)bfhi(b.z); lo[6]=(short)bflo(b.z);
  hi[7]=(short)bfhi(b.w); lo[7]=(short)bflo(b.w);
}
__device__ __forceinline__ float sigf(float x)  { return 1.0f / (1.0f + __expf(-x)); }
__device__ __forceinline__ float tanhf_(float x){ return 1.0f - 2.0f / (__expf(2.0f*x) + 1.0f); }
__device__ __forceinline__ f32x4 mfma16(bf16x8 a, bf16x8 b, f32x4 c) {
  return __builtin_amdgcn_mfma_f32_16x16x32_bf16(a, b, c, 0, 0, 0);
}
// flags[(role*16+bt)*32 + jt] = t+1 once that wg finished step t.
// Lanes 0..7 of wave 0 poll all 8 group flags in one 32B transaction.
__device__ __forceinline__ void spin8(const unsigned* f, unsigned tgt, int lane) {
  for (;;) {
    unsigned v = (lane < 8)
      ? __hip_atomic_load(f + lane, __ATOMIC_RELAXED, __HIP_MEMORY_SCOPE_AGENT)
      : 0xFFFFFFFFu;
    if (!__any(v < tgt)) return;
    __builtin_amdgcn_s_sleep(1);
  }
}

__global__ __launch_bounds__(256, 1)
void lstm_pipe(const float* __restrict__ x,
               const float* __restrict__ w_ih0, const float* __restrict__ w_hh0,
               const float* __restrict__ b_ih0, const float* __restrict__ b_hh0,
               const float* __restrict__ w_ih1, const float* __restrict__ w_hh1,
               const float* __restrict__ b_ih1, const float* __restrict__ b_hh1,
               u16* __restrict__ h1,                               // [256][512][256] bf16
               u16* __restrict__ hex_h, u16* __restrict__ hex_l,   // [2role][2buf][256][256]
               float* __restrict__ h2_last, unsigned* __restrict__ flags)
{
  const int tid  = threadIdx.x;
  const int bx   = blockIdx.x;
  const int role = bx & 1;          // 0: layer0, 1: layer1
  const int bxl  = bx >> 1;
  const int bt   = bxl & 15;        // batch tile (16 rows); sync domain
  const int jt   = bxl >> 4;        // j tile (32 hidden cols -> 128 gate rows)
  const int lane = tid & 63;
  const int wv   = tid >> 6;        // wave 0..3
  const int r16  = lane & 15;
  const int q    = lane >> 4;       // 0..3

  const float* w_ih = role ? w_ih1 : w_ih0;
  const float* w_hh = role ? w_hh1 : w_hh0;
  const float* b_ih = role ? b_ih1 : b_ih0;
  const float* b_hh = role ? b_hh1 : b_hh0;

  // ---- W fragments -> VGPRs, split hi/lo (256 VGPR, held all kernel) ----
  // wave wv owns MFMA n-tiles {2wv,2wv+1}; n_local = j_local*4 + gate, so a
  // lane's 4 acc regs are exactly (i,f,g,o) of one (b,j).
  bf16x8 wih_h[2][8], wih_l[2][8], whh_h[2][8], whh_l[2][8];
  float  bias[2][4];
  float  cst[2] = {0.f, 0.f};
  #pragma unroll
  for (int nt = 0; nt < 2; ++nt) {
    const int Tt = wv*2 + nt, nl = Tt*16 + r16;
    const int gate = nl & 3, jl = nl >> 2;
    const int grow = gate*256 + jt*32 + jl;          // row in w_ih/w_hh
    #pragma unroll
    for (int kt = 0; kt < 8; ++kt) {
      const int k0 = kt*32 + q*8;                    // 8 contiguous k per lane
      const float* pi = w_ih + (size_t)grow*HDIM + k0;
      const float* ph = w_hh + (size_t)grow*HDIM + k0;
      split44(*(const float4*)pi, *(const float4*)(pi+4), wih_h[nt][kt], wih_l[nt][kt]);
      split44(*(const float4*)ph, *(const float4*)(ph+4), whh_h[nt][kt], whh_l[nt][kt]);
    }
    #pragma unroll
    for (int r = 0; r < 4; ++r) {                    // acc reg r -> gate r, j=Tt*4+q
      const int row = r*256 + jt*32 + Tt*4 + q;
      bias[nt][r] = b_ih[row] + b_hh[row];
    }
  }

  const int bg  = bt*16 + r16;                       // this lane's batch row
  const int jg0 = jt*32 + (wv*2+0)*4 + q;
  const int jg1 = jt*32 + (wv*2+1)*4 + q;
  const float* xrow  = x  + (size_t)bg*T_SEQ*HDIM + q*8;
  const u16*   h1row = h1 + (size_t)bg*T_SEQ*HDIM + q*8;
  u16* mhex_h = hex_h + role*2*65536;                // own role's double buffer
  u16* mhex_l = hex_l + role*2*65536;
  const u16* hex_rd_h = mhex_h + (size_t)bg*HDIM + q*8;
  const u16* hex_rd_l = mhex_l + (size_t)bg*HDIM + q*8;
  unsigned*       f_self = flags + (role*16 + bt)*32;
  const unsigned* f_up   = flags + bt*32;            // layer0's flags

  f32x4 acc0, acc1;
  // ---- prologue: acc = bias + Wih-terms(u(0)) ---------------------------
  acc0[0]=bias[0][0]; acc0[1]=bias[0][1]; acc0[2]=bias[0][2]; acc0[3]=bias[0][3];
  acc1[0]=bias[1][0]; acc1[1]=bias[1][1]; acc1[2]=bias[1][2]; acc1[3]=bias[1][3];
  if (role == 0) {                                   // u(0) = x(0): 3-term split
    #pragma unroll
    for (int kt = 0; kt < 8; ++kt) {
      const float* xp = xrow + kt*32;
      bf16x8 uh, ul; split44(*(const float4*)xp, *(const float4*)(xp+4), uh, ul);
      acc0=mfma16(wih_h[0][kt],uh,acc0); acc0=mfma16(wih_h[0][kt],ul,acc0); acc0=mfma16(wih_l[0][kt],uh,acc0);
      acc1=mfma16(wih_h[1][kt],uh,acc1); acc1=mfma16(wih_h[1][kt],ul,acc1); acc1=mfma16(wih_l[1][kt],uh,acc1);
    }
  } else {                                           // u(0) = h1(:,0,:): 2-term
    if (wv == 0) { spin8(f_up, 1u, lane); __builtin_amdgcn_fence(__ATOMIC_ACQUIRE, "agent"); }
    __syncthreads();
    #pragma unroll
    for (int kt = 0; kt < 8; ++kt) {
      bf16x8 ub = *(const bf16x8*)(h1row + kt*32);
      acc0=mfma16(wih_h[0][kt],ub,acc0); acc0=mfma16(wih_l[0][kt],ub,acc0);
      acc1=mfma16(wih_h[1][kt],ub,acc1); acc1=mfma16(wih_l[1][kt],ub,acc1);
    }
  }

  #pragma unroll 1
  for (int t = 0; t < T_SEQ; ++t) {
    // ---- top: wait for own group's h(t-1) ------------------------------
    if (t > 0) {
      if (wv == 0) { spin8(f_self, (unsigned)t, lane); __builtin_amdgcn_fence(__ATOMIC_ACQUIRE, "agent"); }
      __syncthreads();
    }
    // role0: prefetch x(t+1) kts 0..3 now; HBM latency hides under h-path.
    float4 xv0[4], xv1[4];
    if (role == 0 && t < T_SEQ-1) {
      const float* xp = xrow + (size_t)(t+1)*HDIM;
      #pragma unroll
      for (int kt = 0; kt < 4; ++kt) { xv0[kt] = *(const float4*)(xp+kt*32); xv1[kt] = *(const float4*)(xp+kt*32+4); }
    }
    // ---- h-path: acc += Whh-terms(h(t-1)), 3x 8-deep chains ------------
    if (t > 0) {
      const u16* hh = hex_rd_h + (size_t)(t&1)*65536;
      const u16* hl = hex_rd_l + (size_t)(t&1)*65536;
      f32x4 b0={0,0,0,0}, c0={0,0,0,0}, b1={0,0,0,0}, c1={0,0,0,0};
      #pragma unroll
      for (int kt = 0; kt < 8; ++kt) {
        bf16x8 vh = *(const bf16x8*)(hh + kt*32);
        bf16x8 vl = *(const bf16x8*)(hl + kt*32);
        acc0=mfma16(whh_h[0][kt],vh,acc0); b0=mfma16(whh_h[0][kt],vl,b0); c0=mfma16(whh_l[0][kt],vh,c0);
        acc1=mfma16(whh_h[1][kt],vh,acc1); b1=mfma16(whh_h[1][kt],vl,b1); c1=mfma16(whh_l[1][kt],vh,c1);
      }
      acc0 += b0 + c0;
      acc1 += b1 + c1;
    }
    // ---- LSTM cell (fp32, in-register) ---------------------------------
    float i0=sigf(acc0[0]), f0=sigf(acc0[1]), g0=tanhf_(acc0[2]), o0=sigf(acc0[3]);
    cst[0] = f0*cst[0] + i0*g0;
    float hn0 = o0 * tanhf_(cst[0]);
    float i1=sigf(acc1[0]), f1=sigf(acc1[1]), g1=tanhf_(acc1[2]), o1=sigf(acc1[3]);
    cst[1] = f1*cst[1] + i1*g1;
    float hn1 = o1 * tanhf_(cst[1]);

    // ---- publish h (hi/lo for own recurrence; bf16 h1 for layer1) ------
    {
      const size_t oe = (size_t)((t+1)&1)*65536 + (size_t)bg*HDIM;
      mhex_h[oe+jg0] = bfhi(hn0); mhex_l[oe+jg0] = bflo(hn0);
      mhex_h[oe+jg1] = bfhi(hn1); mhex_l[oe+jg1] = bflo(hn1);
      if (role == 0) {
        const size_t o1 = ((size_t)bg*T_SEQ + t)*HDIM;
        h1[o1+jg0] = f2bf(hn0); h1[o1+jg1] = f2bf(hn1);
      } else if (t == T_SEQ-1) {
        h2_last[bg*HDIM + jg0] = hn0; h2_last[bg*HDIM + jg1] = hn1;
      }
    }
    // ---- drain + release signal (fire-and-forget store, no RMW RTT) ----
    __syncthreads();                 // vmcnt(0): all waves' stores in L2
    if (tid == 0)
      __hip_atomic_store(f_self + jt, (unsigned)(t + 1),
                         __ATOMIC_RELEASE, __HIP_MEMORY_SCOPE_AGENT);

    // ---- bottom: u-path for t+1 (overlaps the flag round-trip) ---------
    if (t < T_SEQ-1) {
      acc0[0]=bias[0][0]; acc0[1]=bias[0][1]; acc0[2]=bias[0][2]; acc0[3]=bias[0][3];
      acc1[0]=bias[1][0]; acc1[1]=bias[1][1]; acc1[2]=bias[1][2]; acc1[3]=bias[1][3];
      if (role == 0) {               // x(t+1): 3-term split
        const float* xp = xrow + (size_t)(t+1)*HDIM;
        #pragma unroll
        for (int kt = 0; kt < 4; ++kt) {
          bf16x8 uh, ul; split44(xv0[kt], xv1[kt], uh, ul);
          acc0=mfma16(wih_h[0][kt],uh,acc0); acc0=mfma16(wih_h[0][kt],ul,acc0); acc0=mfma16(wih_l[0][kt],uh,acc0);
          acc1=mfma16(wih_h[1][kt],uh,acc1); acc1=mfma16(wih_h[1][kt],ul,acc1); acc1=mfma16(wih_l[1][kt],uh,acc1);
        }
        #pragma unroll
        for (int kt = 4; kt < 8; ++kt) {
          bf16x8 uh, ul; split44(*(const float4*)(xp+kt*32), *(const float4*)(xp+kt*32+4), uh, ul);
          acc0=mfma16(wih_h[0][kt],uh,acc0); acc0=mfma16(wih_h[0][kt],ul,acc0); acc0=mfma16(wih_l[0][kt],uh,acc0);
          acc1=mfma16(wih_h[1][kt],uh,acc1); acc1=mfma16(wih_h[1][kt],ul,acc1); acc1=mfma16(wih_l[1][kt],uh,acc1);
        }
      } else {                       // h1(:,t+1,:): gated by upstream flags
        if (wv == 0) { spin8(f_up, (unsigned)(t+2), lane); __builtin_amdgcn_fence(__ATOMIC_ACQUIRE, "agent"); }
        __syncthreads();
        const u16* up = h1row + (size_t)(t+1)*HDIM;
        #pragma unroll
        for (int kt = 0; kt < 8; ++kt) {
          bf16x8 ub = *(const bf16x8*)(up + kt*32);
          acc0=mfma16(wih_h[0][kt],ub,acc0); acc0=mfma16(wih_l[0][kt],ub,acc0);
          acc1=mfma16(wih_h[1][kt],ub,acc1); acc1=mfma16(wih_l[1][kt],ub,acc1);
        }
      }
    }
  }
}

__global__ __launch_bounds__(128)
void head_kernel(const float* __restrict__ h2, const float* __restrict__ w_fc,
                 const float* __restrict__ b_fc, float* __restrict__ out)
{
  const int b = blockIdx.x, c = threadIdx.x;   // 256 blocks x 128 threads
  __shared__ float hrow[256];
  __shared__ float red[128];
  hrow[c]       = h2[b*256 + c];
  hrow[c + 128] = h2[b*256 + 128 + c];
  __syncthreads();
  float acc = b_fc[c];
  const float* wr = w_fc + (size_t)c*256;
  #pragma unroll 8
  for (int j = 0; j < 256; ++j) acc += hrow[j] * wr[j];
  red[c] = acc; __syncthreads();
  for (int s = 64; s; s >>= 1) { if (c < s) red[c] = fmaxf(red[c], red[c+s]); __syncthreads(); }
  const float m = red[0]; __syncthreads();
  red[c] = __expf(acc - m); __syncthreads();
  for (int s = 64; s; s >>= 1) { if (c < s) red[c] += red[c+s]; __syncthreads(); }
  out[b*128 + c] = acc - m - __logf(red[0]);
}

extern "C" void kernel_launch(void* const* d_in, const int* in_sizes, int n_in,
                              void* d_out, int out_size, void* d_ws, size_t ws_size,
                              hipStream_t stream) {
  const float* x     = (const float*)d_in[0];
  const float* w_ih0 = (const float*)d_in[1];
  const float* w_hh0 = (const float*)d_in[2];
  const float* b_ih0 = (const float*)d_in[3];
  const float* b_hh0 = (const float*)d_in[4];
  const float* w_ih1 = (const float*)d_in[5];
  const float* w_hh1 = (const float*)d_in[6];
  const float* b_ih1 = (const float*)d_in[7];
  const float* b_hh1 = (const float*)d_in[8];
  const float* w_fc  = (const float*)d_in[9];
  const float* b_fc  = (const float*)d_in[10];
  float* out = (float*)d_out;

  // workspace layout (need = 2 MiB + 64 MiB):
  //   [0,       4 KiB)  flags  [2][16][32] u32
  //   [8 KiB, 264 KiB)  h2_last fp32 [256][256]
  //   [512 KiB, 1 MiB)  hex_h  [2][2][256][256] bf16
  //   [1 MiB, 1.5 MiB)  hex_l  [2][2][256][256] bf16
  //   [2 MiB, 66 MiB)   h1     [256][512][256] bf16
  const size_t NEED = (2ull << 20) + (64ull << 20);
  if (ws_size < NEED) return;      // visible validation failure, not OOB

  char* ws = (char*)d_ws;
  unsigned* flags = (unsigned*)(ws);
  float* h2       = (float*)(ws + 8192);
  u16*   hex_h    = (u16*)(ws + (512ull << 10));
  u16*   hex_l    = (u16*)(ws + (1ull << 20));
  u16*   h1       = (u16*)(ws + (2ull << 20));

  hipMemsetAsync(flags, 0, 4096, stream);            // zero sync flags

  lstm_pipe<<<dim3(256), dim3(256), 0, stream>>>(
      x, w_ih0, w_hh0, b_ih0, b_hh0, w_ih1, w_hh1, b_ih1, b_hh1,
      h1, hex_h, hex_l, h2, flags);
  head_kernel<<<dim3(256), dim3(128), 0, stream>>>(h2, w_fc, b_fc, out);
}